// Round 8
// baseline (343.100 us; speedup 1.0000x reference)
//
#include <hip/hip_runtime.h>

typedef __attribute__((ext_vector_type(8))) short short8;
typedef __attribute__((ext_vector_type(4))) float floatx4;

#define D 128
#define NWAVES 4
#define NB 512            // source buckets (256 nodes each; covers nNodes<=131072)
#define SORT_CAP 524288   // g_sorted capacity

// bf16 MFMA B-fragment buffer for W1,W2: 2*128*128 bf16 = 64 KB.
__device__ unsigned short g_wq[2 * D * D];
// edge bucket-sort state
__device__ int g_cnt[NB];
__device__ int g_cur[NB];
__device__ int g_sorted[SORT_CAP];

__device__ __forceinline__ unsigned short f2bf(float f) {
  unsigned u = __float_as_uint(f);
  u += 0x7FFFu + ((u >> 16) & 1u);   // RNE
  return (unsigned short)(u >> 16);
}

// One-shot W prep (W ONLY) + zero bucket counters (block 0).
// g_wq[layer*16384 + fragid*512 + lane*8 + e] =
//   W[(kk*32+(lane>>4)*8+e)*D + n0*16+(lane&15)]
__global__ __launch_bounds__(256) void prep_w(const float* __restrict__ W1,
                                              const float* __restrict__ W2) {
  if (blockIdx.x == 0) {
    for (int i = threadIdx.x; i < NB; i += 256) g_cnt[i] = 0;
  }
  const int t = blockIdx.x * 256 + threadIdx.x;   // 32768 total
  const int layer = t >> 14;
  const int r = t & 16383;
  const int fragid = r >> 9;          // kk*8 + n0, [0,32)
  const int lane = (r >> 3) & 63;
  const int e = r & 7;
  const int kk = fragid >> 3, n0 = fragid & 7;
  const int k = kk * 32 + (lane >> 4) * 8 + e;    // [0,128)
  const int n = n0 * 16 + (lane & 15);            // [0,128)
  const float* W = layer ? W2 : W1;
  g_wq[t] = f2bf(W[k * D + n]);
}

// --- edge bucket sort: hist -> scan -> scatter (s-locality for the gather) ---
__global__ __launch_bounds__(256) void e_hist(const int* __restrict__ eidx, int E) {
  __shared__ int lc[NB];
  for (int i = threadIdx.x; i < NB; i += 256) lc[i] = 0;
  __syncthreads();
  for (int e = blockIdx.x * 256 + threadIdx.x; e < E; e += gridDim.x * 256)
    atomicAdd(&lc[(((unsigned)eidx[e]) >> 8) & (NB - 1)], 1);
  __syncthreads();
  for (int i = threadIdx.x; i < NB; i += 256)
    if (lc[i]) atomicAdd(&g_cnt[i], lc[i]);
}

__global__ __launch_bounds__(NB) void e_scan() {
  __shared__ int tmp[NB];
  const int t = threadIdx.x;
  const int v = g_cnt[t];
  tmp[t] = v;
  __syncthreads();
  #pragma unroll
  for (int off = 1; off < NB; off <<= 1) {
    int add = (t >= off) ? tmp[t - off] : 0;
    __syncthreads();
    tmp[t] += add;
    __syncthreads();
  }
  g_cur[t] = tmp[t] - v;   // exclusive prefix = bucket cursor start
}

__global__ __launch_bounds__(256) void e_scatter(const int* __restrict__ eidx, int E) {
  for (int e = blockIdx.x * 256 + threadIdx.x; e < E; e += gridDim.x * 256) {
    const int b = (((unsigned)eidx[e]) >> 8) & (NB - 1);
    const int pos = atomicAdd(&g_cur[b], 1);
    g_sorted[pos] = e;
  }
}

__device__ __forceinline__ short8 cvt_a(const floatx4& f0, const floatx4& f1) {
  short8 a;
  a[0] = (short)f2bf(f0[0]); a[1] = (short)f2bf(f0[1]);
  a[2] = (short)f2bf(f0[2]); a[3] = (short)f2bf(f0[3]);
  a[4] = (short)f2bf(f1[0]); a[5] = (short)f2bf(f1[1]);
  a[6] = (short)f2bf(f1[2]); a[7] = (short)f2bf(f1[3]);
  return a;
}

// Fused 2-layer MLP (unchanged from r5/r6: B-frags prefetched to registers).
__global__ __launch_bounds__(256, 2) void mlp_fused(
    const float* __restrict__ x,
    const float* __restrict__ b1, const float* __restrict__ b2,
    unsigned short* __restrict__ h, int nNodes, int npairs) {
  __shared__ unsigned short sH[NWAVES][16 * D];  // 16 KB total
  const int tid = threadIdx.x;
  const int wave = tid >> 6, lane = tid & 63;
  const int quad = lane >> 4, l16 = lane & 15;

  const int p = blockIdx.x * NWAVES + wave;
  if (p >= npairs) return;

  const short8* wq1 = (const short8*)g_wq;
  const short8* wq2 = (const short8*)(g_wq + 16384);
  unsigned short* mysH = sH[wave];

  const int mbase = p * 32;
  const int m0 = mbase + l16;
  const int m1 = m0 + 16;
  short8 a0[4], a1[4];
  {
    const floatx4* xp0 = (const floatx4*)(x + (size_t)m0 * D + quad * 8);
    const floatx4* xp1 = (const floatx4*)(x + (size_t)m1 * D + quad * 8);
    const bool v0 = (m0 < nNodes), v1 = (m1 < nNodes);
    floatx4 xf0[8], xf1[8];
    #pragma unroll
    for (int i = 0; i < 8; ++i) {
      const int o = (i >> 1) * 8 + (i & 1);
      xf0[i] = v0 ? xp0[o] : (floatx4){0.f, 0.f, 0.f, 0.f};
      xf1[i] = v1 ? xp1[o] : (floatx4){0.f, 0.f, 0.f, 0.f};
    }
    #pragma unroll
    for (int kk = 0; kk < 4; ++kk) {
      a0[kk] = cvt_a(xf0[2 * kk], xf0[2 * kk + 1]);
      a1[kk] = cvt_a(xf1[2 * kk], xf1[2 * kk + 1]);
    }
  }
  short8 bf[32];
  #pragma unroll
  for (int i = 0; i < 32; ++i) bf[i] = wq1[i * 64 + lane];
  __builtin_amdgcn_sched_barrier(0);
  floatx4 acc0[8], acc1[8];
  #pragma unroll
  for (int n0 = 0; n0 < 8; ++n0) {
    acc0[n0] = (floatx4){0.f, 0.f, 0.f, 0.f};
    acc1[n0] = (floatx4){0.f, 0.f, 0.f, 0.f};
  }
  #pragma unroll
  for (int kk = 0; kk < 4; ++kk) {
    #pragma unroll
    for (int n0 = 0; n0 < 8; ++n0) {
      acc0[n0] = __builtin_amdgcn_mfma_f32_16x16x32_bf16(a0[kk], bf[kk * 8 + n0], acc0[n0], 0, 0, 0);
      acc1[n0] = __builtin_amdgcn_mfma_f32_16x16x32_bf16(a1[kk], bf[kk * 8 + n0], acc1[n0], 0, 0, 0);
    }
  }
  __builtin_amdgcn_sched_barrier(0);
  #pragma unroll
  for (int i = 0; i < 32; ++i) bf[i] = wq2[i * 64 + lane];
  __builtin_amdgcn_sched_barrier(0);
  float bias1[8];
  #pragma unroll
  for (int n0 = 0; n0 < 8; ++n0) bias1[n0] = b1[n0 * 16 + l16];
  short8 af0[4], af1[4];
  #pragma unroll
  for (int n0 = 0; n0 < 8; ++n0) {
    #pragma unroll
    for (int r = 0; r < 4; ++r) {
      float v = acc0[n0][r] + bias1[n0];
      v = v > 0.f ? v : 0.f;
      const int row = quad * 4 + r;
      const int g = 2 * n0 + (l16 >> 3);
      mysH[row * D + (((g ^ row) & 15) << 3) + (l16 & 7)] = f2bf(v);
    }
  }
  #pragma unroll
  for (int kk = 0; kk < 4; ++kk)
    af0[kk] = *(const short8*)&mysH[l16 * D + ((((kk * 4 + quad) ^ l16) & 15) << 3)];
  #pragma unroll
  for (int n0 = 0; n0 < 8; ++n0) {
    #pragma unroll
    for (int r = 0; r < 4; ++r) {
      float v = acc1[n0][r] + bias1[n0];
      v = v > 0.f ? v : 0.f;
      const int row = quad * 4 + r;
      const int g = 2 * n0 + (l16 >> 3);
      mysH[row * D + (((g ^ row) & 15) << 3) + (l16 & 7)] = f2bf(v);
    }
  }
  #pragma unroll
  for (int kk = 0; kk < 4; ++kk)
    af1[kk] = *(const short8*)&mysH[l16 * D + ((((kk * 4 + quad) ^ l16) & 15) << 3)];
  #pragma unroll
  for (int n0 = 0; n0 < 8; ++n0) {
    acc0[n0] = (floatx4){0.f, 0.f, 0.f, 0.f};
    acc1[n0] = (floatx4){0.f, 0.f, 0.f, 0.f};
  }
  #pragma unroll
  for (int kk = 0; kk < 4; ++kk) {
    #pragma unroll
    for (int n0 = 0; n0 < 8; ++n0) {
      acc0[n0] = __builtin_amdgcn_mfma_f32_16x16x32_bf16(af0[kk], bf[kk * 8 + n0], acc0[n0], 0, 0, 0);
      acc1[n0] = __builtin_amdgcn_mfma_f32_16x16x32_bf16(af1[kk], bf[kk * 8 + n0], acc1[n0], 0, 0, 0);
    }
  }
  __builtin_amdgcn_sched_barrier(0);
  float bias2[8];
  #pragma unroll
  for (int n0 = 0; n0 < 8; ++n0) bias2[n0] = b2[n0 * 16 + l16];
  #pragma unroll
  for (int n0 = 0; n0 < 8; ++n0) {
    #pragma unroll
    for (int r = 0; r < 4; ++r) {
      float v = acc0[n0][r] + bias2[n0];
      v = v > 0.f ? v : 0.f;
      const int row = quad * 4 + r;
      const int g = 2 * n0 + (l16 >> 3);
      mysH[row * D + (((g ^ row) & 15) << 3) + (l16 & 7)] = f2bf(v);
    }
  }
  #pragma unroll
  for (int i = 0; i < 4; ++i) {
    const int row = i * 4 + quad;
    short8 vrow = *(const short8*)&mysH[row * D + (((l16 ^ row) & 15) << 3)];
    const int g = mbase + row;
    if (g < nNodes) *(short8*)&h[(size_t)g * D + l16 * 8] = vrow;
  }
  #pragma unroll
  for (int n0 = 0; n0 < 8; ++n0) {
    #pragma unroll
    for (int r = 0; r < 4; ++r) {
      float v = acc1[n0][r] + bias2[n0];
      v = v > 0.f ? v : 0.f;
      const int row = quad * 4 + r;
      const int g = 2 * n0 + (l16 >> 3);
      mysH[row * D + (((g ^ row) & 15) << 3) + (l16 & 7)] = f2bf(v);
    }
  }
  #pragma unroll
  for (int i = 0; i < 4; ++i) {
    const int row = i * 4 + quad;
    short8 vrow = *(const short8*)&mysH[row * D + (((l16 ^ row) & 15) << 3)];
    const int g = mbase + 16 + row;
    if (g < nNodes) *(short8*)&h[(size_t)g * D + l16 * 8] = vrow;
  }
}

__device__ __forceinline__ float dot2bf(unsigned a, unsigned b, float acc) {
  float a0 = __uint_as_float(a << 16);
  float a1 = __uint_as_float(a & 0xFFFF0000u);
  float b0 = __uint_as_float(b << 16);
  float b1 = __uint_as_float(b & 0xFFFF0000u);
  acc = fmaf(a0, b0, acc);
  acc = fmaf(a1, b1, acc);
  return acc;
}

__device__ __forceinline__ float edge_dot(const uint4& a, const uint4& b) {
  float acc = 0.f;
  acc = dot2bf(a.x, b.x, acc);
  acc = dot2bf(a.y, b.y, acc);
  acc = dot2bf(a.z, b.z, acc);
  acc = dot2bf(a.w, b.w, acc);
  acc += __shfl_xor(acc, 8);
  acc += __shfl_xor(acc, 4);
  acc += __shfl_xor(acc, 2);
  acc += __shfl_xor(acc, 1);
  return acc;
}

// Edge decode in BUCKET-SORTED order: s-gathers of a bucket (256 nodes,
// 64 KB of h) reuse within a ~650 KB window -> L2-resident. XCD chunk
// swizzle keeps consecutive sorted blocks on one XCD's private L2.
// Labels folded in (streaming, hides under gather latency).
__global__ __launch_bounds__(256) void edge_kernel(
    const unsigned short* __restrict__ h2, const int* __restrict__ eidx,
    const int* __restrict__ elabel, float* __restrict__ out, int E,
    int use_sorted) {
  const int tid = threadIdx.x;
  const int t = blockIdx.x * 256 + tid;
  {
    const int E4 = E & ~3;
    for (int li = t * 4; li < E4; li += gridDim.x * 256 * 4) {
      int4 lv = *(const int4*)&elabel[li];
      float4 fv = make_float4((float)lv.x, (float)lv.y, (float)lv.z, (float)lv.w);
      *(float4*)&out[E + li] = fv;
    }
    if (t < (E & 3)) out[E + E4 + t] = (float)elabel[E4 + t];
  }
  // XCD chunk swizzle (gridDim.x is a multiple of 8): logical block lb
  const int q = gridDim.x >> 3;
  const int lb = (blockIdx.x & 7) * q + (blockIdx.x >> 3);
  const int sub = tid & 15;
  const int grp = (lb * 256 + tid) >> 4;
  const int e0 = grp * 8;
  if (e0 + 8 <= E) {
    int ei[8];
    if (use_sorted) {
      const int4 i0 = *(const int4*)&g_sorted[e0];
      const int4 i1 = *(const int4*)&g_sorted[e0 + 4];
      ei[0]=i0.x; ei[1]=i0.y; ei[2]=i0.z; ei[3]=i0.w;
      ei[4]=i1.x; ei[5]=i1.y; ei[6]=i1.z; ei[7]=i1.w;
    } else {
      #pragma unroll
      for (int i = 0; i < 8; ++i) ei[i] = e0 + i;
    }
    int s[8], d[8];
    #pragma unroll
    for (int i = 0; i < 8; ++i) { s[i] = eidx[ei[i]]; d[i] = eidx[E + ei[i]]; }
    uint4 va[8], vb[8];
    #pragma unroll
    for (int i = 0; i < 8; ++i) {
      va[i] = *(const uint4*)(h2 + (((size_t)(unsigned)s[i]) << 7) + sub * 8);
      vb[i] = *(const uint4*)(h2 + (((size_t)(unsigned)d[i]) << 7) + sub * 8);
    }
    #pragma unroll
    for (int i = 0; i < 8; ++i) {
      float acc = edge_dot(va[i], vb[i]);
      if (sub == 0) out[ei[i]] = acc;
    }
  } else if (e0 < E) {
    for (int e = e0; e < E; ++e) {
      const int id = use_sorted ? g_sorted[e] : e;
      const int s = eidx[id];
      const int d = eidx[E + id];
      const uint4 ua = *(const uint4*)(h2 + (((size_t)(unsigned)s) << 7) + sub * 8);
      const uint4 ub = *(const uint4*)(h2 + (((size_t)(unsigned)d) << 7) + sub * 8);
      float acc = edge_dot(ua, ub);
      if (sub == 0) out[id] = acc;
    }
  }
}

extern "C" void kernel_launch(void* const* d_in, const int* in_sizes, int n_in,
                              void* d_out, int out_size, void* d_ws, size_t ws_size,
                              hipStream_t stream) {
  const float* x  = (const float*)d_in[0];
  const int* eidx = (const int*)d_in[1];
  const int* elab = (const int*)d_in[2];
  const float* W1 = (const float*)d_in[3];
  const float* b1 = (const float*)d_in[4];
  const float* W2 = (const float*)d_in[5];
  const float* b2 = (const float*)d_in[6];
  float* out = (float*)d_out;

  const int nNodes = in_sizes[0] / D;   // 100000
  const int E = in_sizes[2];            // 500000
  const int npairs = (nNodes + 31) / 32;
  const int use_sorted = (E <= SORT_CAP) ? 1 : 0;

  unsigned short* h = (unsigned short*)d_ws;  // nNodes*128 bf16 = 25.6 MB

  prep_w<<<128, 256, 0, stream>>>(W1, W2);   // W frags + zero g_cnt

  if (use_sorted) {
    e_hist<<<256, 256, 0, stream>>>(eidx, E);
    e_scan<<<1, NB, 0, stream>>>();
    e_scatter<<<256, 256, 0, stream>>>(eidx, E);
  }

  const int nblk = (npairs + NWAVES - 1) / NWAVES;  // 782
  mlp_fused<<<nblk, 256, 0, stream>>>(x, b1, b2, h, nNodes, npairs);

  int eb = (E + 127) / 128;            // 128 edges per block
  eb = (eb + 7) & ~7;                  // multiple of 8 for the XCD swizzle
  edge_kernel<<<eb, 256, 0, stream>>>(h, eidx, elab, out, E, use_sorted);
}

// Round 9
// 149.516 us; speedup vs baseline: 2.2947x; 2.2947x over previous
//
#include <hip/hip_runtime.h>

typedef __attribute__((ext_vector_type(8))) short short8;
typedef __attribute__((ext_vector_type(4))) float floatx4;

#define D 128
#define NWAVES 4

// bf16 MFMA B-fragment buffer for W1,W2: 2*128*128 bf16 = 64 KB.
__device__ unsigned short g_wq[2 * D * D];

__device__ __forceinline__ unsigned short f2bf(float f) {
  unsigned u = __float_as_uint(f);
  u += 0x7FFFu + ((u >> 16) & 1u);   // RNE
  return (unsigned short)(u >> 16);
}

// One-shot W prep: fp32 W1,W2 -> bf16 MFMA B-fragment order.
// g_wq[layer*16384 + fragid*512 + lane*8 + e] =
//   W[(kk*32+(lane>>4)*8+e)*D + n0*16+(lane&15)]
__global__ __launch_bounds__(256) void prep_w(const float* __restrict__ W1,
                                              const float* __restrict__ W2) {
  const int t = blockIdx.x * 256 + threadIdx.x;   // 32768 total
  const int layer = t >> 14;
  const int r = t & 16383;
  const int fragid = r >> 9;          // kk*8 + n0, [0,32)
  const int lane = (r >> 3) & 63;
  const int e = r & 7;
  const int kk = fragid >> 3, n0 = fragid & 7;
  const int k = kk * 32 + (lane >> 4) * 8 + e;    // [0,128)
  const int n = n0 * 16 + (lane & 15);            // [0,128)
  const float* W = layer ? W2 : W1;
  g_wq[t] = f2bf(W[k * D + n]);
}

__device__ __forceinline__ short8 cvt_a(const floatx4& f0, const floatx4& f1) {
  short8 a;
  a[0] = (short)f2bf(f0[0]); a[1] = (short)f2bf(f0[1]);
  a[2] = (short)f2bf(f0[2]); a[3] = (short)f2bf(f0[3]);
  a[4] = (short)f2bf(f1[0]); a[5] = (short)f2bf(f1[1]);
  a[6] = (short)f2bf(f1[2]); a[7] = (short)f2bf(f1[3]);
  return a;
}

// Fused 2-layer MLP, 16 rows/wave (r8 occupancy fix): B-prefetch split into
// two 16-fragment groups (bf[16]=64 VGPR vs bf[32]=128) -> live set ~164 regs
// -> __launch_bounds__(256,3) = 3 waves/SIMD (was 2). Two extra ~250ns L2-hot
// load exposures per layer, bought +50% latency hiding + 2x wave count.
__global__ __launch_bounds__(256, 3) void mlp_fused(
    const float* __restrict__ x,
    const float* __restrict__ b1, const float* __restrict__ b2,
    unsigned short* __restrict__ h, int nNodes, int ntiles) {
  __shared__ unsigned short sH[NWAVES][16 * D];  // 16 KB total
  const int tid = threadIdx.x;
  const int wave = tid >> 6, lane = tid & 63;
  const int quad = lane >> 4, l16 = lane & 15;

  const int p = blockIdx.x * NWAVES + wave;
  if (p >= ntiles) return;

  const short8* wq1 = (const short8*)g_wq;
  const short8* wq2 = (const short8*)(g_wq + 16384);
  unsigned short* mysH = sH[wave];

  const int mbase = p * 16;
  const int m0 = mbase + l16;
  // Load 16 rows of x (8x 16B per thread), convert to A-frags immediately.
  short8 a[4];
  {
    const floatx4* xp = (const floatx4*)(x + (size_t)m0 * D + quad * 8);
    const bool v = (m0 < nNodes);
    floatx4 xf[8];
    #pragma unroll
    for (int i = 0; i < 8; ++i) {
      const int o = (i >> 1) * 8 + (i & 1);
      xf[i] = v ? xp[o] : (floatx4){0.f, 0.f, 0.f, 0.f};
    }
    #pragma unroll
    for (int kk = 0; kk < 4; ++kk) a[kk] = cvt_a(xf[2 * kk], xf[2 * kk + 1]);
  }
  // ---- layer 1 (two n0-groups) ----
  floatx4 acc[8];
  #pragma unroll
  for (int n0 = 0; n0 < 8; ++n0) acc[n0] = (floatx4){0.f, 0.f, 0.f, 0.f};
  short8 bf[16];
  #pragma unroll
  for (int kk = 0; kk < 4; ++kk)
    #pragma unroll
    for (int j = 0; j < 4; ++j) bf[kk * 4 + j] = wq1[(kk * 8 + j) * 64 + lane];
  __builtin_amdgcn_sched_barrier(0);
  #pragma unroll
  for (int kk = 0; kk < 4; ++kk)
    #pragma unroll
    for (int j = 0; j < 4; ++j)
      acc[j] = __builtin_amdgcn_mfma_f32_16x16x32_bf16(a[kk], bf[kk * 4 + j], acc[j], 0, 0, 0);
  __builtin_amdgcn_sched_barrier(0);
  #pragma unroll
  for (int kk = 0; kk < 4; ++kk)
    #pragma unroll
    for (int j = 0; j < 4; ++j) bf[kk * 4 + j] = wq1[(kk * 8 + 4 + j) * 64 + lane];
  __builtin_amdgcn_sched_barrier(0);
  #pragma unroll
  for (int kk = 0; kk < 4; ++kk)
    #pragma unroll
    for (int j = 0; j < 4; ++j)
      acc[4 + j] = __builtin_amdgcn_mfma_f32_16x16x32_bf16(a[kk], bf[kk * 4 + j], acc[4 + j], 0, 0, 0);
  __builtin_amdgcn_sched_barrier(0);
  // epilogue 1 -> sH (swizzled transpose), then read A-frags
  float bias1[8];
  #pragma unroll
  for (int n0 = 0; n0 < 8; ++n0) bias1[n0] = b1[n0 * 16 + l16];
  #pragma unroll
  for (int n0 = 0; n0 < 8; ++n0) {
    #pragma unroll
    for (int r = 0; r < 4; ++r) {
      float v = acc[n0][r] + bias1[n0];
      v = v > 0.f ? v : 0.f;
      const int row = quad * 4 + r;
      const int g = 2 * n0 + (l16 >> 3);
      mysH[row * D + (((g ^ row) & 15) << 3) + (l16 & 7)] = f2bf(v);
    }
  }
  short8 af[4];
  #pragma unroll
  for (int kk = 0; kk < 4; ++kk)
    af[kk] = *(const short8*)&mysH[l16 * D + ((((kk * 4 + quad) ^ l16) & 15) << 3)];
  // ---- layer 2 (two n0-groups) ----
  #pragma unroll
  for (int n0 = 0; n0 < 8; ++n0) acc[n0] = (floatx4){0.f, 0.f, 0.f, 0.f};
  #pragma unroll
  for (int kk = 0; kk < 4; ++kk)
    #pragma unroll
    for (int j = 0; j < 4; ++j) bf[kk * 4 + j] = wq2[(kk * 8 + j) * 64 + lane];
  __builtin_amdgcn_sched_barrier(0);
  #pragma unroll
  for (int kk = 0; kk < 4; ++kk)
    #pragma unroll
    for (int j = 0; j < 4; ++j)
      acc[j] = __builtin_amdgcn_mfma_f32_16x16x32_bf16(af[kk], bf[kk * 4 + j], acc[j], 0, 0, 0);
  __builtin_amdgcn_sched_barrier(0);
  #pragma unroll
  for (int kk = 0; kk < 4; ++kk)
    #pragma unroll
    for (int j = 0; j < 4; ++j) bf[kk * 4 + j] = wq2[(kk * 8 + 4 + j) * 64 + lane];
  __builtin_amdgcn_sched_barrier(0);
  #pragma unroll
  for (int kk = 0; kk < 4; ++kk)
    #pragma unroll
    for (int j = 0; j < 4; ++j)
      acc[4 + j] = __builtin_amdgcn_mfma_f32_16x16x32_bf16(af[kk], bf[kk * 4 + j], acc[4 + j], 0, 0, 0);
  __builtin_amdgcn_sched_barrier(0);
  // epilogue 2 + store
  float bias2[8];
  #pragma unroll
  for (int n0 = 0; n0 < 8; ++n0) bias2[n0] = b2[n0 * 16 + l16];
  #pragma unroll
  for (int n0 = 0; n0 < 8; ++n0) {
    #pragma unroll
    for (int r = 0; r < 4; ++r) {
      float v = acc[n0][r] + bias2[n0];
      v = v > 0.f ? v : 0.f;
      const int row = quad * 4 + r;
      const int g = 2 * n0 + (l16 >> 3);
      mysH[row * D + (((g ^ row) & 15) << 3) + (l16 & 7)] = f2bf(v);
    }
  }
  #pragma unroll
  for (int i = 0; i < 4; ++i) {
    const int row = i * 4 + quad;
    short8 vrow = *(const short8*)&mysH[row * D + (((l16 ^ row) & 15) << 3)];
    const int g = mbase + row;
    if (g < nNodes) *(short8*)&h[(size_t)g * D + l16 * 8] = vrow;
  }
}

__device__ __forceinline__ float dot2bf(unsigned a, unsigned b, float acc) {
  float a0 = __uint_as_float(a << 16);
  float a1 = __uint_as_float(a & 0xFFFF0000u);
  float b0 = __uint_as_float(b << 16);
  float b1 = __uint_as_float(b & 0xFFFF0000u);
  acc = fmaf(a0, b0, acc);
  acc = fmaf(a1, b1, acc);
  return acc;
}

__device__ __forceinline__ float edge_dot(const uint4& a, const uint4& b) {
  float acc = 0.f;
  acc = dot2bf(a.x, b.x, acc);
  acc = dot2bf(a.y, b.y, acc);
  acc = dot2bf(a.z, b.z, acc);
  acc = dot2bf(a.w, b.w, acc);
  acc += __shfl_xor(acc, 8);
  acc += __shfl_xor(acc, 4);
  acc += __shfl_xor(acc, 2);
  acc += __shfl_xor(acc, 1);
  return acc;
}

// Edge decode (r6-identical, sort REVERTED): 16 lanes/edge, 8 edges per
// group -> 16 gathers (256B) in flight. Labels folded in (streaming,
// hides under gather latency).
__global__ __launch_bounds__(256) void edge_kernel(
    const unsigned short* __restrict__ h2, const int* __restrict__ eidx,
    const int* __restrict__ elabel, float* __restrict__ out, int E) {
  const int t = blockIdx.x * 256 + threadIdx.x;
  {
    const int E4 = E & ~3;
    for (int li = t * 4; li < E4; li += gridDim.x * 256 * 4) {
      int4 lv = *(const int4*)&elabel[li];
      float4 fv = make_float4((float)lv.x, (float)lv.y, (float)lv.z, (float)lv.w);
      *(float4*)&out[E + li] = fv;
    }
    if (t < (E & 3)) out[E + E4 + t] = (float)elabel[E4 + t];
  }
  const int sub = threadIdx.x & 15;
  const int grp = t >> 4;
  const int e0 = grp * 8;
  if (e0 + 8 <= E) {
    const int4 s0 = *(const int4*)&eidx[e0];
    const int4 s1 = *(const int4*)&eidx[e0 + 4];
    const int4 t0 = *(const int4*)&eidx[E + e0];
    const int4 t1 = *(const int4*)&eidx[E + e0 + 4];
    int s[8] = {s0.x, s0.y, s0.z, s0.w, s1.x, s1.y, s1.z, s1.w};
    int d[8] = {t0.x, t0.y, t0.z, t0.w, t1.x, t1.y, t1.z, t1.w};
    uint4 va[8], vb[8];
    #pragma unroll
    for (int i = 0; i < 8; ++i) {
      va[i] = *(const uint4*)(h2 + (((size_t)(unsigned)s[i]) << 7) + sub * 8);
      vb[i] = *(const uint4*)(h2 + (((size_t)(unsigned)d[i]) << 7) + sub * 8);
    }
    #pragma unroll
    for (int i = 0; i < 8; ++i) {
      float acc = edge_dot(va[i], vb[i]);
      if (sub == 0) out[e0 + i] = acc;
    }
  } else if (e0 < E) {
    for (int e = e0; e < E; ++e) {
      const int s = eidx[e];
      const int d = eidx[E + e];
      const uint4 ua = *(const uint4*)(h2 + (((size_t)(unsigned)s) << 7) + sub * 8);
      const uint4 ub = *(const uint4*)(h2 + (((size_t)(unsigned)d) << 7) + sub * 8);
      float acc = edge_dot(ua, ub);
      if (sub == 0) out[e] = acc;
    }
  }
}

extern "C" void kernel_launch(void* const* d_in, const int* in_sizes, int n_in,
                              void* d_out, int out_size, void* d_ws, size_t ws_size,
                              hipStream_t stream) {
  const float* x  = (const float*)d_in[0];
  const int* eidx = (const int*)d_in[1];
  const int* elab = (const int*)d_in[2];
  const float* W1 = (const float*)d_in[3];
  const float* b1 = (const float*)d_in[4];
  const float* W2 = (const float*)d_in[5];
  const float* b2 = (const float*)d_in[6];
  float* out = (float*)d_out;

  const int nNodes = in_sizes[0] / D;   // 100000
  const int E = in_sizes[2];            // 500000
  const int ntiles = (nNodes + 15) / 16;  // 6250 16-row tiles

  unsigned short* h = (unsigned short*)d_ws;  // nNodes*128 bf16 = 25.6 MB

  prep_w<<<128, 256, 0, stream>>>(W1, W2);

  const int nblk = (ntiles + NWAVES - 1) / NWAVES;  // 1563: one tile per wave
  mlp_fused<<<nblk, 256, 0, stream>>>(x, b1, b2, h, nNodes, ntiles);

  const int edgeBlocks = (E + 127) / 128;   // 8 edges per 16-lane group
  edge_kernel<<<edgeBlocks, 256, 0, stream>>>(h, eidx, elab, out, E);
}